// Round 7
// baseline (345.340 us; speedup 1.0000x reference)
//
#include <hip/hip_runtime.h>
#include <hip/hip_bf16.h>
#include <stdint.h>

// Problem dims: B=4, S=2048 -> M=8192; IN=K=4096; OUT=N=4096; R=16
#define M_DIM 8192
#define N_DIM 4096
#define K_DIM 4096
#define R_DIM 16

typedef __bf16 bf16x8 __attribute__((ext_vector_type(8)));
typedef float f32x4 __attribute__((ext_vector_type(4)));
typedef unsigned short u16x8 __attribute__((ext_vector_type(8)));

#define AS1(p) ((const __attribute__((address_space(1))) void*)(p))
#define AS3(p) ((__attribute__((address_space(3))) void*)(p))

#define BAR()    __builtin_amdgcn_s_barrier()
#define LGKM0()  asm volatile("s_waitcnt lgkmcnt(0)")
#define VMCNT3() asm volatile("s_waitcnt vmcnt(3)")
#define VMCNT0() asm volatile("s_waitcnt vmcnt(0)")
#define SCHED0() __builtin_amdgcn_sched_barrier(0)

__device__ __forceinline__ unsigned short f2bf(float f) {
  unsigned u = __builtin_bit_cast(unsigned, f);
  u += 0x7FFFu + ((u >> 16) & 1u);   // round-to-nearest-even
  return (unsigned short)(u >> 16);
}

// ---------------------------------------------------------------------------
// prep: blocks [0,1024): awb[o,i] = bf16(W[o,i]*(1+sum_r A[r,i]*B[o,r]))
//       blocks [1024,5120): xb = bf16(x), vectorized grid-stride
// ---------------------------------------------------------------------------
#define CVT_BLOCKS 4096
__global__ void __launch_bounds__(256) prep_kernel(
    const float* __restrict__ x, const float* __restrict__ W,
    const float* __restrict__ lA, const float* __restrict__ lB,
    unsigned short* __restrict__ xb, unsigned short* __restrict__ awb) {
  __shared__ float Asub[16 * 512];
  __shared__ float Bsub[32 * 16];
  const int tid = threadIdx.x;

  if (blockIdx.x < 1024) {
    const int i0 = (blockIdx.x & 7) * 512;
    const int o0 = (blockIdx.x >> 3) * 32;
    for (int idx = tid; idx < 16 * 512; idx += 256) {
      int r = idx >> 9, i = idx & 511;
      Asub[idx] = lA[r * K_DIM + i0 + i];
    }
    for (int idx = tid; idx < 32 * 16; idx += 256) {
      int o = idx >> 4, r = idx & 15;
      Bsub[idx] = lB[(o0 + o) * R_DIM + r];
    }
    __syncthreads();
    for (int idx = tid; idx < 32 * 512; idx += 256) {
      int o = idx >> 9, i = idx & 511;
      float s = 1.0f;
#pragma unroll
      for (int r = 0; r < 16; ++r) s += Asub[r * 512 + i] * Bsub[o * 16 + r];
      size_t g = (size_t)(o0 + o) * K_DIM + i0 + i;
      awb[g] = f2bf(W[g] * s);
    }
  } else {
    const long total = (long)M_DIM * K_DIM;
    long i = ((long)(blockIdx.x - 1024) * 256 + tid) * 8;
    const long stride = (long)CVT_BLOCKS * 256 * 8;
    for (; i < total; i += stride) {
      const float4* p = (const float4*)(x + i);
      float4 f0 = p[0], f1 = p[1];
      u16x8 v;
      v[0] = f2bf(f0.x); v[1] = f2bf(f0.y); v[2] = f2bf(f0.z); v[3] = f2bf(f0.w);
      v[4] = f2bf(f1.x); v[5] = f2bf(f1.y); v[6] = f2bf(f1.z); v[7] = f2bf(f1.w);
      *(u16x8*)(xb + i) = v;
    }
  }
}

// ---------------------------------------------------------------------------
// GEMM: out[m,n] = sum_k xb[m,k]*awb[n,k] + bias[n]
// 256x128 tile, BK=32, 8 waves (4Mx2N), per-wave 64x64 (acc[4][4]=64 VGPR).
// 48KB LDS + launch_bounds(512,4) -> VGPR<=128 -> 2 INDEPENDENT blocks/CU
// (4 waves/SIMD): cross-block drift overlaps one block's LDS-read window
// with the other's MFMA window (m114 mechanism) -- breaking the in-block
// read/MFMA serialization measured in R3-R6 (LDS 48% + MFMA 53% = 101%).
// Per K-tile: reads(8 b128) | lgkm0+sched0 | BAR1 | stage(t+2, 3 gll) |
// 16 MFMA | vmcnt(3) | BAR2. Counted vmcnt keeps t+1,t+2 in flight (never
// drains to 0 mid-loop). WAR ledger: stage(t+2->buf) issues only after BAR1,
// which every wave reaches only after lgkm-draining its reads of buf.
// vmcnt FIFO: at wait, outstanding = t+1(3) + t+2(3) = 6 -> vmcnt(3)
// publishes exactly tile t+1 (cover: staged one full K-tile earlier).
// st_16x32-style XOR swizzle (T2): element (r,c) of a 16r x 32c subtile at
// byte (r*64+c*2)^((r&8)<<2); gload_lds writes linearly so the global source
// col is pre-permuted with the same involution (rule 21).
// ---------------------------------------------------------------------------
#define BM 256
#define BN 128
#define BK 32
#define NT (K_DIM / BK)   // 128

__global__ void __launch_bounds__(512, 4) gemm_kernel(
    const unsigned short* __restrict__ Ag,   // [M][K] bf16 bits (x)
    const unsigned short* __restrict__ Bg,   // [N][K] bf16 bits (adapted W)
    const float* __restrict__ bias,
    float* __restrict__ out) {
  // 2 bufs x (A 16KB + B 8KB) = 48KB
  __shared__ __attribute__((aligned(16))) char LDS[2 * 24576];

  // Bijective XCD swizzle: grid = 32*32 = 1024, 1024 % 8 == 0.
  const int nwg = gridDim.x;
  const int q8 = nwg >> 3;
  const int wg = blockIdx.x;
  const int swz = (wg & 7) * q8 + (wg >> 3);
  const int tiles_n = N_DIM / BN;            // 32
  const int brow = (swz / tiles_n) * BM;
  const int bcol = (swz % tiles_n) * BN;

  const int tid = threadIdx.x;
  const int lane = tid & 63;
  const int w = tid >> 6;                    // wave 0..7
  const int wr = w >> 1, wc = w & 1;         // 4M x 2N wave grid
  const int fr = lane & 15;
  const int kq = (lane >> 4) << 3;           // 0,8,16,24

  // staging source map (inverse swizzle): lane covers subtile bytes l*16
  const int rr = lane >> 2;                               // row in 16-row group
  const int c_sw = ((lane & 3) << 3) ^ (((lane >> 5) & 1) << 4);

  // A: 16KB = 2 issues; issue i covers rowgroups i*8 + w. B: 8KB = 1 issue.
  const unsigned short* srcA0 = Ag + (size_t)(brow + (0 * 8 + w) * 16 + rr) * K_DIM + c_sw;
  const unsigned short* srcA1 = Ag + (size_t)(brow + (1 * 8 + w) * 16 + rr) * K_DIM + c_sw;
  const unsigned short* srcB  = Bg + (size_t)(bcol + w * 16 + rr) * K_DIM + c_sw;

  auto stage = [&](int buf, int kt) {        // 3 gll per wave
    const size_t ko = (size_t)kt * BK;
    __builtin_amdgcn_global_load_lds(AS1(srcA0 + ko), AS3(LDS + buf * 24576 + w * 1024), 16, 0, 0);
    __builtin_amdgcn_global_load_lds(AS1(srcA1 + ko), AS3(LDS + buf * 24576 + 8192 + w * 1024), 16, 0, 0);
    __builtin_amdgcn_global_load_lds(AS1(srcB  + ko), AS3(LDS + buf * 24576 + 16384 + w * 1024), 16, 0, 0);
  };

  // swizzled ds_read byte offset within a 1KB subtile
  const int rdsw = (fr * 64 + kq * 2) ^ ((fr & 8) << 2);

  f32x4 acc[4][4] = {};
  bf16x8 a[4], b[4];

  auto read_frags = [&](int buf) {
#pragma unroll
    for (int m = 0; m < 4; ++m)
      a[m] = *(const bf16x8*)(LDS + buf * 24576 + (wr * 4 + m) * 1024 + rdsw);
#pragma unroll
    for (int n = 0; n < 4; ++n)
      b[n] = *(const bf16x8*)(LDS + buf * 24576 + 16384 + (wc * 4 + n) * 1024 + rdsw);
  };
  auto mma_all = [&]() {
#pragma unroll
    for (int m = 0; m < 4; ++m)
#pragma unroll
      for (int n = 0; n < 4; ++n)
        acc[m][n] = __builtin_amdgcn_mfma_f32_16x16x32_bf16(a[m], b[n], acc[m][n], 0, 0, 0);
  };

  auto body = [&](int t, int buf) {
    read_frags(buf);                 // 8 x ds_read_b128
    LGKM0(); SCHED0();               // reads executed before BAR1 (WAR pin)
    BAR();                           // BAR1: whole block done reading buf
    if (t < NT - 2) stage(buf, t + 2);
    __builtin_amdgcn_s_setprio(1); mma_all(); __builtin_amdgcn_s_setprio(0);
    if (t < NT - 2) { VMCNT3(); }    // publishes tile t+1, keeps t+2 in flight
    else if (t == NT - 2) { VMCNT0(); }
    SCHED0();
    BAR();                           // BAR2: t+1 visible to all waves
  };

  // prologue: stage t0 -> buf0, t1 -> buf1; per-wave 6 gll; wait own t0
  stage(0, 0); stage(1, 1);
  VMCNT3();
  BAR();

#pragma unroll 1
  for (int i = 0; i < NT / 2; ++i) {
    body(2 * i, 0);
    body(2 * i + 1, 1);
  }

  // epilogue: C/D map col = lane&15, row = (lane>>4)*4 + j
  const int fq = (lane >> 4) * 4;
#pragma unroll
  for (int n = 0; n < 4; ++n) {
    const int col = bcol + wc * 64 + n * 16 + fr;
    const float bb = bias[col];
#pragma unroll
    for (int m = 0; m < 4; ++m) {
      const int row = brow + wr * 64 + m * 16 + fq;
      f32x4 v = acc[m][n];
#pragma unroll
      for (int j = 0; j < 4; ++j)
        out[(size_t)(row + j) * N_DIM + col] = v[j] + bb;
    }
  }
}

// ---------------------------------------------------------------------------
extern "C" void kernel_launch(void* const* d_in, const int* in_sizes, int n_in,
                              void* d_out, int out_size, void* d_ws, size_t ws_size,
                              hipStream_t stream) {
  const float* x    = (const float*)d_in[0];
  const float* W    = (const float*)d_in[1];
  const float* bias = (const float*)d_in[2];
  const float* lA   = (const float*)d_in[3];
  const float* lB   = (const float*)d_in[4];
  float* out = (float*)d_out;

  unsigned short* xb  = (unsigned short*)d_ws;            // 64 MiB
  unsigned short* awb = xb + (size_t)M_DIM * K_DIM;       // 32 MiB

  prep_kernel<<<1024 + CVT_BLOCKS, 256, 0, stream>>>(x, W, lA, lB, xb, awb);
  gemm_kernel<<<(M_DIM / BM) * (N_DIM / BN), 512, 0, stream>>>(xb, awb, bias, out);
}

// Round 8
// 297.120 us; speedup vs baseline: 1.1623x; 1.1623x over previous
//
#include <hip/hip_runtime.h>
#include <hip/hip_bf16.h>
#include <stdint.h>

// Problem dims: B=4, S=2048 -> M=8192; IN=K=4096; OUT=N=4096; R=16
#define M_DIM 8192
#define N_DIM 4096
#define K_DIM 4096
#define R_DIM 16

typedef __bf16 bf16x8 __attribute__((ext_vector_type(8)));
typedef float f32x4 __attribute__((ext_vector_type(4)));
typedef unsigned short u16x8 __attribute__((ext_vector_type(8)));

#define AS1(p) ((const __attribute__((address_space(1))) void*)(p))
#define AS3(p) ((__attribute__((address_space(3))) void*)(p))

// R4-style macros (fastest measured): asm fences around barrier keep the
// compiler from migrating plain LDS derefs across phases.
#define BAR() do { asm volatile("" ::: "memory"); __builtin_amdgcn_s_barrier(); asm volatile("" ::: "memory"); } while (0)
#define VMCNT2() asm volatile("s_waitcnt vmcnt(2)" ::: "memory")
#define VMCNT0() asm volatile("s_waitcnt vmcnt(0)" ::: "memory")
#define VMCNT8() asm volatile("s_waitcnt vmcnt(8)" ::: "memory")

__device__ __forceinline__ unsigned short f2bf(float f) {
  unsigned u = __builtin_bit_cast(unsigned, f);
  u += 0x7FFFu + ((u >> 16) & 1u);   // round-to-nearest-even
  return (unsigned short)(u >> 16);
}

// ---------------------------------------------------------------------------
// prep: blocks [0,1024): awb[o,i] = bf16(W[o,i]*(1+sum_r A[r,i]*B[o,r]))
//       blocks [1024,5120): xb = bf16(x), vectorized grid-stride
// ---------------------------------------------------------------------------
#define CVT_BLOCKS 4096
__global__ void __launch_bounds__(256) prep_kernel(
    const float* __restrict__ x, const float* __restrict__ W,
    const float* __restrict__ lA, const float* __restrict__ lB,
    unsigned short* __restrict__ xb, unsigned short* __restrict__ awb) {
  __shared__ float Asub[16 * 512];
  __shared__ float Bsub[32 * 16];
  const int tid = threadIdx.x;

  if (blockIdx.x < 1024) {
    const int i0 = (blockIdx.x & 7) * 512;
    const int o0 = (blockIdx.x >> 3) * 32;
    for (int idx = tid; idx < 16 * 512; idx += 256) {
      int r = idx >> 9, i = idx & 511;
      Asub[idx] = lA[r * K_DIM + i0 + i];
    }
    for (int idx = tid; idx < 32 * 16; idx += 256) {
      int o = idx >> 4, r = idx & 15;
      Bsub[idx] = lB[(o0 + o) * R_DIM + r];
    }
    __syncthreads();
    for (int idx = tid; idx < 32 * 512; idx += 256) {
      int o = idx >> 9, i = idx & 511;
      float s = 1.0f;
#pragma unroll
      for (int r = 0; r < 16; ++r) s += Asub[r * 512 + i] * Bsub[o * 16 + r];
      size_t g = (size_t)(o0 + o) * K_DIM + i0 + i;
      awb[g] = f2bf(W[g] * s);
    }
  } else {
    const long total = (long)M_DIM * K_DIM;
    long i = ((long)(blockIdx.x - 1024) * 256 + tid) * 8;
    const long stride = (long)CVT_BLOCKS * 256 * 8;
    for (; i < total; i += stride) {
      const float4* p = (const float4*)(x + i);
      float4 f0 = p[0], f1 = p[1];
      u16x8 v;
      v[0] = f2bf(f0.x); v[1] = f2bf(f0.y); v[2] = f2bf(f0.z); v[3] = f2bf(f0.w);
      v[4] = f2bf(f1.x); v[5] = f2bf(f1.y); v[6] = f2bf(f1.z); v[7] = f2bf(f1.w);
      *(u16x8*)(xb + i) = v;
    }
  }
}

// ---------------------------------------------------------------------------
// GEMM: out[m,n] = sum_k xb[m,k]*awb[n,k] + bias[n]
// 256x256 tile, BK=64, 8 waves (2Mx4N). R4 read-ahead structure with phases
// merged 4->2 per K-tile: 2 barriers/tile, 32 MFMA per barrier (AITER ratio).
// Ledger (tile t, buf=t&1; Q0:a_lo*b_lo Q1:a_lo*b_hi Q2:a_hi*b_hi Q3:a_hi*b_lo):
//  A: stage buf.B0<-t+2 | mma Q0,Q1 | read a_hi(t) | vmcnt(2) | BAR
//  B: stage buf.B1,A0,A1<-t+2 | mma Q2,Q3 | read b_hi,a_lo,b_lo(t+1) | BAR
// Register WAR: every fragment read is program-order after its last MFMA use
//  (read a_hi after Q1; read_bhi after Q2; read_a/read_blo after Q3).
// LDS WAR: stage B0(t+2)->buf overwrites b_lo region, last ds_read in B(t-1)
//  (1 BAR + write-latency margin, same placement class R4 proved); stage
//  B1/A0/A1 in B(t) sit 1-2 BARs after their regions' last reads.
// vmcnt FIFO at A(t)'s wait: outstanding <= [t+1: 8][B0(t+2): 2] = 10;
//  vmcnt(2) completes all of tile t+1 before B(t)'s cross-buffer reads.
// ---------------------------------------------------------------------------
__global__ void __launch_bounds__(512, 2) gemm_kernel(
    const unsigned short* __restrict__ Ag,   // [M][K] bf16 bits (x)
    const unsigned short* __restrict__ Bg,   // [N][K] bf16 bits (adapted W)
    const float* __restrict__ bias,
    float* __restrict__ out) {
  __shared__ __attribute__((aligned(16))) unsigned short LDS[2 * 32768];

  // Bijective XCD swizzle: grid = 32*16 = 512, 512 % 8 == 0.
  const int nwg = gridDim.x;
  const int q8 = nwg >> 3;
  const int wg = blockIdx.x;
  const int swz = (wg & 7) * q8 + (wg >> 3);
  const int tiles_n = N_DIM / 256;           // 16
  const int brow = (swz / tiles_n) * 256;
  const int bcol = (swz % tiles_n) * 256;

  const int tid = threadIdx.x;
  const int lane = tid & 63;
  const int w = tid >> 6;                    // wave 0..7
  const int wr = w >> 2, wc = w & 3;         // 2 x 4 wave grid
  const int fr = lane & 15;
  const int kq = (lane >> 4) << 3;           // 0,8,16,24

  // staging source map (inverse of st_16x32 swizzle)
  const int rr = lane >> 2;
  const int cc = ((lane & 1) << 3) | ((((lane >> 1) ^ (lane >> 5)) & 1) << 4);
  const int c_sw = ((w & 1) << 5) | cc;
  const int rbase = ((w >> 1) << 4) + rr;

  const unsigned short* srcA[2][2];          // [half][q]
#pragma unroll
  for (int h = 0; h < 2; ++h)
#pragma unroll
    for (int q = 0; q < 2; ++q)
      srcA[h][q] = Ag + (size_t)(brow + h * 128 + q * 64 + rbase) * K_DIM + c_sw;
  const long long bdelta = (long long)(Bg - Ag) + (long long)(bcol - brow) * K_DIM;

  auto stageA = [&](int buf, int h, int kt) {
#pragma unroll
    for (int q = 0; q < 2; ++q)
      __builtin_amdgcn_global_load_lds(AS1(srcA[h][q] + (size_t)kt * 64),
          AS3(&LDS[buf * 32768 + h * 8192 + q * 4096 + w * 512]), 16, 0, 0);
  };
  auto stageB = [&](int buf, int h, int kt) {
#pragma unroll
    for (int q = 0; q < 2; ++q)
      __builtin_amdgcn_global_load_lds(AS1(srcA[h][q] + bdelta + (size_t)kt * 64),
          AS3(&LDS[buf * 32768 + 16384 + h * 8192 + q * 4096 + w * 512]), 16, 0, 0);
  };

  // swizzled ds_read addressing
  const int rdsw = ((fr << 6) | (kq << 1)) ^ ((fr & 8) << 2);
  auto lda = [&](int buf, int m, int kk) -> bf16x8 {
    return *(const bf16x8*)((const char*)LDS +
        (buf * 65536 + wr * 16384 + (m * 2 + kk) * 1024 + rdsw));
  };
  auto ldb = [&](int buf, int n, int kk) -> bf16x8 {
    return *(const bf16x8*)((const char*)LDS +
        (buf * 65536 + 32768 + (wc >> 1) * 16384 +
         (((wc & 1) * 4 + n) * 2 + kk) * 1024 + rdsw));
  };

  f32x4 acc[8][4] = {};
  bf16x8 a[2][4];          // current A half (a_lo -> a_hi in-place per tile)
  bf16x8 blo[2][2], bhi[2][2];

  auto read_a = [&](int buf, int mg) {       // mg=0: a_lo, mg=4: a_hi
#pragma unroll
    for (int kk = 0; kk < 2; ++kk)
#pragma unroll
      for (int mi = 0; mi < 4; ++mi)
        a[kk][mi] = lda(buf, mg + mi, kk);
  };
  auto read_blo = [&](int buf) {
#pragma unroll
    for (int kk = 0; kk < 2; ++kk)
#pragma unroll
      for (int ni = 0; ni < 2; ++ni)
        blo[kk][ni] = ldb(buf, ni, kk);
  };
  auto read_bhi = [&](int buf) {
#pragma unroll
    for (int kk = 0; kk < 2; ++kk)
#pragma unroll
      for (int ni = 0; ni < 2; ++ni)
        bhi[kk][ni] = ldb(buf, 2 + ni, kk);
  };
  auto mma_b = [&](bf16x8 (&bb)[2][2], int am, int an) {
#pragma unroll
    for (int mi = 0; mi < 4; ++mi)
#pragma unroll
      for (int ni = 0; ni < 2; ++ni)
#pragma unroll
        for (int kk = 0; kk < 2; ++kk)
          acc[am + mi][an + ni] = __builtin_amdgcn_mfma_f32_16x16x32_bf16(
              a[kk][mi], bb[kk][ni], acc[am + mi][an + ni], 0, 0, 0);
  };

  // one tile = 2 phases; g2: stage t+2 exists; gr: tile t+1 exists
  auto tile_body = [&](int t, int buf, bool g2, bool gr) {
    const int nxbuf = buf ^ 1;
    // Phase A
    if (g2) stageB(buf, 0, t + 2);
    __builtin_amdgcn_s_setprio(1);
    mma_b(blo, 0, 0); mma_b(bhi, 0, 2);
    __builtin_amdgcn_s_setprio(0);
    read_a(buf, 4);                          // a_hi(t), after Q1's last use of a_lo
    if (g2) { VMCNT2(); } else { VMCNT0(); } // publishes tile t+1
    BAR();
    // Phase B
    if (g2) { stageB(buf, 1, t + 2); stageA(buf, 0, t + 2); stageA(buf, 1, t + 2); }
    __builtin_amdgcn_s_setprio(1);
    mma_b(bhi, 4, 2); mma_b(blo, 4, 0);
    __builtin_amdgcn_s_setprio(0);
    if (gr) { read_bhi(nxbuf); read_a(nxbuf, 0); read_blo(nxbuf); }  // t+1 frags
    BAR();
  };

  // prologue: stage tiles 0 (buf0) and 1 (buf1); wait tile0; pre-read frags
  stageB(0, 0, 0); stageB(0, 1, 0); stageA(0, 0, 0); stageA(0, 1, 0);
  stageB(1, 0, 1); stageB(1, 1, 1); stageA(1, 0, 1); stageA(1, 1, 1);
  VMCNT8();
  BAR();
  read_bhi(0); read_a(0, 0); read_blo(0);    // tile0: b_hi, a_lo, b_lo

  // main loop: 32 pairs of tiles (NT = 64)
#pragma unroll 1
  for (int i = 0; i < 32; ++i) {
    const bool more = (i < 31);
    tile_body(2 * i,     0, more, true);
    tile_body(2 * i + 1, 1, more, more);
  }

  // epilogue: C/D map col = lane&15, row = (lane>>4)*4 + j
  const int fq = (lane >> 4) * 4;
#pragma unroll
  for (int n = 0; n < 4; ++n) {
    const int col = bcol + wc * 64 + n * 16 + fr;
    const float bb = bias[col];
#pragma unroll
    for (int m = 0; m < 8; ++m) {
      const int row = brow + wr * 128 + m * 16 + fq;
      f32x4 v = acc[m][n];
#pragma unroll
      for (int j = 0; j < 4; ++j)
        out[(size_t)(row + j) * N_DIM + col] = v[j] + bb;
    }
  }
}

// ---------------------------------------------------------------------------
extern "C" void kernel_launch(void* const* d_in, const int* in_sizes, int n_in,
                              void* d_out, int out_size, void* d_ws, size_t ws_size,
                              hipStream_t stream) {
  const float* x    = (const float*)d_in[0];
  const float* W    = (const float*)d_in[1];
  const float* bias = (const float*)d_in[2];
  const float* lA   = (const float*)d_in[3];
  const float* lB   = (const float*)d_in[4];
  float* out = (float*)d_out;

  unsigned short* xb  = (unsigned short*)d_ws;            // 64 MiB
  unsigned short* awb = xb + (size_t)M_DIM * K_DIM;       // 32 MiB

  prep_kernel<<<1024 + CVT_BLOCKS, 256, 0, stream>>>(x, W, lA, lB, xb, awb);
  gemm_kernel<<<(M_DIM / 256) * (N_DIM / 256), 512, 0, stream>>>(xb, awb, bias, out);
}